// Round 1
// baseline (4152.689 us; speedup 1.0000x reference)
//
#include <hip/hip_runtime.h>

// LSTMForecaster: B=2048, S=512, IN=1, H=64, OUT=72, 2 LSTM layers + FC.
// Fused persistent kernel: each block owns BT=8 batch rows, iterates all 512
// timesteps for both layers. Weights in registers (192 f32/thread), states in LDS.

#define BATCH 2048
#define SEQ   512
#define HIDN  64
#define GATES 256   // 4*H
#define NOUT  72
#define BT    8     // batch rows per block
#define NT    256   // threads per block (== GATES)

__device__ __forceinline__ float fast_rcp(float x) { return __builtin_amdgcn_rcpf(x); }
__device__ __forceinline__ float sigm(float x)   { return fast_rcp(1.f + __expf(-x)); }
__device__ __forceinline__ float tanh_f(float x) { return 1.f - 2.f * fast_rcp(__expf(2.f * x) + 1.f); }

__global__ __launch_bounds__(NT, 1)
void lstm2_fused_kernel(const float* __restrict__ x,     // [B,S,1]
                        const float* __restrict__ wih0,  // [256,1]
                        const float* __restrict__ whh0,  // [256,64]
                        const float* __restrict__ bih0,  // [256]
                        const float* __restrict__ bhh0,  // [256]
                        const float* __restrict__ wih1,  // [256,64]
                        const float* __restrict__ whh1,  // [256,64]
                        const float* __restrict__ bih1,  // [256]
                        const float* __restrict__ bhh1,  // [256]
                        const float* __restrict__ fcw,   // [72,64]
                        const float* __restrict__ fcb,   // [72]
                        float* __restrict__ out)         // [B,72]
{
    const int t  = threadIdx.x;          // gate unit index g = t
    const int b0 = blockIdx.x * BT;

    __shared__ float x_lds[BT][SEQ];     // 16 KB
    __shared__ float h0_lds[BT][HIDN];   // 2 KB
    __shared__ float h1_lds[BT][HIDN];   // 2 KB
    __shared__ float g_lds[BT][GATES];   // 8 KB

    // ---- weights into registers (constant-indexed, fully unrolled) ----
    float w0[HIDN], wi1[HIDN], wh1[HIDN];
    #pragma unroll
    for (int k = 0; k < HIDN; ++k) w0[k]  = whh0[t * HIDN + k];
    #pragma unroll
    for (int k = 0; k < HIDN; ++k) wi1[k] = wih1[t * HIDN + k];
    #pragma unroll
    for (int k = 0; k < HIDN; ++k) wh1[k] = whh1[t * HIDN + k];
    const float wx0 = wih0[t];
    const float bs0 = bih0[t] + bhh0[t];
    const float bs1 = bih1[t] + bhh1[t];

    // ---- stage x for our batch rows; zero states ----
    for (int i = t; i < BT * SEQ; i += NT) {
        int b = i >> 9, s = i & (SEQ - 1);
        x_lds[b][s] = x[(size_t)(b0 + b) * SEQ + s];
    }
    for (int i = t; i < BT * HIDN; i += NT) {
        h0_lds[i >> 6][i & 63] = 0.f;
        h1_lds[i >> 6][i & 63] = 0.f;
    }

    const int hid = t & 63;
    const int bA  = t >> 6;              // 0..3 ; thread also handles bA+4
    float c0a = 0.f, c0b = 0.f, c1a = 0.f, c1b = 0.f;
    const bool tanh_gate = (t >= 128) && (t < 192);   // wave-uniform

    __syncthreads();

    #pragma unroll 1
    for (int s = 0; s < SEQ; ++s) {
        float acc[BT];

        // ======== phase A: layer-0 gates: bs0 + x*wih0 + h0 @ Whh0^T ========
        #pragma unroll
        for (int b = 0; b < BT; ++b) acc[b] = fmaf(wx0, x_lds[b][s], bs0);
        #pragma unroll
        for (int k4 = 0; k4 < HIDN / 4; ++k4) {
            #pragma unroll
            for (int b = 0; b < BT; ++b) {
                float4 h = *(const float4*)&h0_lds[b][k4 * 4];
                acc[b] = fmaf(h.x, w0[k4*4+0], acc[b]);
                acc[b] = fmaf(h.y, w0[k4*4+1], acc[b]);
                acc[b] = fmaf(h.z, w0[k4*4+2], acc[b]);
                acc[b] = fmaf(h.w, w0[k4*4+3], acc[b]);
            }
        }
        if (tanh_gate) {
            #pragma unroll
            for (int b = 0; b < BT; ++b) g_lds[b][t] = tanh_f(acc[b]);
        } else {
            #pragma unroll
            for (int b = 0; b < BT; ++b) g_lds[b][t] = sigm(acc[b]);
        }
        __syncthreads();

        // ======== phase B: layer-0 state update (2 (b,hid) items/thread) ====
        {
            float i1 = g_lds[bA][hid],       f1 = g_lds[bA][64 + hid];
            float gg1 = g_lds[bA][128 + hid], o1 = g_lds[bA][192 + hid];
            c0a = fmaf(f1, c0a, i1 * gg1);
            h0_lds[bA][hid] = o1 * tanh_f(c0a);

            float i2 = g_lds[bA+4][hid],       f2 = g_lds[bA+4][64 + hid];
            float gg2 = g_lds[bA+4][128 + hid], o2 = g_lds[bA+4][192 + hid];
            c0b = fmaf(f2, c0b, i2 * gg2);
            h0_lds[bA+4][hid] = o2 * tanh_f(c0b);
        }
        __syncthreads();

        // ======== phase C: layer-1 gates: bs1 + h0new @ Wih1^T + h1 @ Whh1^T
        #pragma unroll
        for (int b = 0; b < BT; ++b) acc[b] = bs1;
        #pragma unroll
        for (int k4 = 0; k4 < HIDN / 4; ++k4) {
            #pragma unroll
            for (int b = 0; b < BT; ++b) {
                float4 h = *(const float4*)&h0_lds[b][k4 * 4];
                acc[b] = fmaf(h.x, wi1[k4*4+0], acc[b]);
                acc[b] = fmaf(h.y, wi1[k4*4+1], acc[b]);
                acc[b] = fmaf(h.z, wi1[k4*4+2], acc[b]);
                acc[b] = fmaf(h.w, wi1[k4*4+3], acc[b]);
            }
        }
        #pragma unroll
        for (int k4 = 0; k4 < HIDN / 4; ++k4) {
            #pragma unroll
            for (int b = 0; b < BT; ++b) {
                float4 h = *(const float4*)&h1_lds[b][k4 * 4];
                acc[b] = fmaf(h.x, wh1[k4*4+0], acc[b]);
                acc[b] = fmaf(h.y, wh1[k4*4+1], acc[b]);
                acc[b] = fmaf(h.z, wh1[k4*4+2], acc[b]);
                acc[b] = fmaf(h.w, wh1[k4*4+3], acc[b]);
            }
        }
        if (tanh_gate) {
            #pragma unroll
            for (int b = 0; b < BT; ++b) g_lds[b][t] = tanh_f(acc[b]);
        } else {
            #pragma unroll
            for (int b = 0; b < BT; ++b) g_lds[b][t] = sigm(acc[b]);
        }
        __syncthreads();

        // ======== phase D: layer-1 state update ========
        {
            float i1 = g_lds[bA][hid],       f1 = g_lds[bA][64 + hid];
            float gg1 = g_lds[bA][128 + hid], o1 = g_lds[bA][192 + hid];
            c1a = fmaf(f1, c1a, i1 * gg1);
            h1_lds[bA][hid] = o1 * tanh_f(c1a);

            float i2 = g_lds[bA+4][hid],       f2 = g_lds[bA+4][64 + hid];
            float gg2 = g_lds[bA+4][128 + hid], o2 = g_lds[bA+4][192 + hid];
            c1b = fmaf(f2, c1b, i2 * gg2);
            h1_lds[bA+4][hid] = o2 * tanh_f(c1b);
        }
        __syncthreads();
    }

    // ======== FC: out = h1[S-1] @ fc_w^T + fc_b ========
    for (int idx = t; idx < BT * NOUT; idx += NT) {
        int b = idx / NOUT, o = idx - b * NOUT;
        float a = fcb[o];
        #pragma unroll
        for (int k = 0; k < HIDN; ++k) a = fmaf(h1_lds[b][k], fcw[o * HIDN + k], a);
        out[(size_t)(b0 + b) * NOUT + o] = a;
    }
}

extern "C" void kernel_launch(void* const* d_in, const int* in_sizes, int n_in,
                              void* d_out, int out_size, void* d_ws, size_t ws_size,
                              hipStream_t stream) {
    const float* x    = (const float*)d_in[0];
    const float* wih0 = (const float*)d_in[1];
    const float* whh0 = (const float*)d_in[2];
    const float* bih0 = (const float*)d_in[3];
    const float* bhh0 = (const float*)d_in[4];
    const float* wih1 = (const float*)d_in[5];
    const float* whh1 = (const float*)d_in[6];
    const float* bih1 = (const float*)d_in[7];
    const float* bhh1 = (const float*)d_in[8];
    const float* fcw  = (const float*)d_in[9];
    const float* fcb  = (const float*)d_in[10];
    float* out = (float*)d_out;

    dim3 grid(BATCH / BT);   // 256 blocks -> 1 per CU
    dim3 block(NT);
    hipLaunchKernelGGL(lstm2_fused_kernel, grid, block, 0, stream,
                       x, wih0, whh0, bih0, bhh0, wih1, whh1, bih1, bhh1,
                       fcw, fcb, out);
}